// Round 9
// baseline (1554.124 us; speedup 1.0000x reference)
//
#include <hip/hip_runtime.h>

// Problem constants (fixed by the reference)
#define BB    8
#define NN    8192
#define MM    2048
#define CFEAT 64
#define OUTC  128
#define NS    32
#define NBUCK 128     // buckets per batch; bucket j owned by wave (j & 7)
#define FPS_T 512     // 8 waves

// ---------------------------------------------------------------------------
// DPP wave64 reductions. row_shr k within 16-lane rows; bcast15/31 cross rows.
// bound_ctrl=false + old=self => shifted-out lanes contribute identity.
// ---------------------------------------------------------------------------
template<int C, int R>
__device__ __forceinline__ float dpp_maxf(float v) {
    int t = __builtin_amdgcn_update_dpp(__float_as_int(v), __float_as_int(v), C, R, 0xf, false);
    return fmaxf(v, __int_as_float(t));
}
template<int C, int R>
__device__ __forceinline__ float dpp_minf(float v) {
    int t = __builtin_amdgcn_update_dpp(__float_as_int(v), __float_as_int(v), C, R, 0xf, false);
    return fminf(v, __int_as_float(t));
}
template<int C, int R>
__device__ __forceinline__ unsigned long long dpp_maxu64(unsigned long long v) {
    unsigned lo = (unsigned)v, hi = (unsigned)(v >> 32);
    unsigned tlo = (unsigned)__builtin_amdgcn_update_dpp((int)lo, (int)lo, C, R, 0xf, false);
    unsigned thi = (unsigned)__builtin_amdgcn_update_dpp((int)hi, (int)hi, C, R, 0xf, false);
    unsigned long long t = ((unsigned long long)thi << 32) | tlo;
    return t > v ? t : v;
}
__device__ __forceinline__ float wred_maxf(float v) {
    v = dpp_maxf<0x111,0xf>(v); v = dpp_maxf<0x112,0xf>(v);
    v = dpp_maxf<0x114,0xf>(v); v = dpp_maxf<0x118,0xf>(v);
    v = dpp_maxf<0x142,0xa>(v); v = dpp_maxf<0x143,0xc>(v);
    return __int_as_float(__builtin_amdgcn_readlane(__float_as_int(v), 63));
}
__device__ __forceinline__ float wred_minf(float v) {
    v = dpp_minf<0x111,0xf>(v); v = dpp_minf<0x112,0xf>(v);
    v = dpp_minf<0x114,0xf>(v); v = dpp_minf<0x118,0xf>(v);
    v = dpp_minf<0x142,0xa>(v); v = dpp_minf<0x143,0xc>(v);
    return __int_as_float(__builtin_amdgcn_readlane(__float_as_int(v), 63));
}
// full 64-lane chain + broadcast lane63 to all lanes
__device__ __forceinline__ unsigned long long wbcast_maxu64(unsigned long long v) {
    v = dpp_maxu64<0x111,0xf>(v); v = dpp_maxu64<0x112,0xf>(v);
    v = dpp_maxu64<0x114,0xf>(v); v = dpp_maxu64<0x118,0xf>(v);
    v = dpp_maxu64<0x142,0xa>(v); v = dpp_maxu64<0x143,0xc>(v);
    unsigned lo = (unsigned)__builtin_amdgcn_readlane((int)(unsigned)v, 63);
    unsigned hi = (unsigned)__builtin_amdgcn_readlane((int)(unsigned)(v >> 32), 63);
    return ((unsigned long long)hi << 32) | lo;
}
// 16-lane row reduction: lane 15 (31,47,63) holds max over its row
__device__ __forceinline__ unsigned long long row16_maxu64(unsigned long long v) {
    v = dpp_maxu64<0x111,0xf>(v); v = dpp_maxu64<0x112,0xf>(v);
    v = dpp_maxu64<0x114,0xf>(v); v = dpp_maxu64<0x118,0xf>(v);
    return v;
}

// identical fma shape for point distance and bbox lower bound => lb2 <= d2
// holds in f32 by per-op monotonicity (safe exact skipping).
__device__ __forceinline__ float distsq(float dx, float dy, float dz) {
    return fmaf(dz, dz, fmaf(dy, dy, dx * dx));
}

// key layout: (dmin_bits << 32) | ((8191-orig) << 13) | pos
// u64 max  =>  max dmin, ties -> min orig (orig unique => total order).
// Validated bit-exact in R5-R8.
__device__ __forceinline__ unsigned long long pack_key(float dmn, unsigned orig, unsigned pos) {
    return ((unsigned long long)__float_as_uint(dmn) << 32)
         | ((unsigned long long)(8191u - orig) << 13) | pos;
}

// ---------------------------------------------------------------------------
// LDS layout (byte offsets), FPS path:
//   spt    [8192] float4 (x,y,z,dmin)       0   131072 B
//   sorig  [8192] u16               131072    16384 B
//   skey   [2][8] u64 (per-WAVE max, parity) 147456   128 B
//   s_misc [4] i32                  147584       16 B
// total 147600 -> alloc 147712. bbox + per-bucket keys live in REGISTERS.
// ---------------------------------------------------------------------------
#define FPS_LDS_BYTES 147712

__global__ __launch_bounds__(FPS_T) void fps_featw_kernel(
    const float* __restrict__ xyz, const int* __restrict__ key_mask,
    const float* __restrict__ feat, const float* __restrict__ W,
    int* __restrict__ fps_idx, float* __restrict__ G)
{
    extern __shared__ float sm[];
    const int t    = threadIdx.x;
    const int lane = t & 63;
    const int w    = t >> 6;

    if (blockIdx.x >= BB) {
        // ------- featW path: 32 blocks x 8 waves x 256 pts -------
        float* Wt = sm;   // [c][o], 32 KB
        for (int i = t; i < CFEAT * OUTC; i += FPS_T) {
            int c = i >> 7, o = i & 127;
            Wt[i] = W[o * 67 + c];
        }
        __syncthreads();
        const int p0 = (blockIdx.x - BB) * 2048 + w * 256;
        for (int k = 0; k < 256; k += 2) {
            int pA = p0 + k, pB = pA + 1;
            float fa = feat[(size_t)pA * CFEAT + lane];
            float fb = feat[(size_t)pB * CFEAT + lane];
            float a0 = 0.f, a1 = 0.f, b0 = 0.f, b1 = 0.f;
            #pragma unroll 8
            for (int c = 0; c < CFEAT; ++c) {
                float ca = __shfl(fa, c), cb = __shfl(fb, c);
                float w0 = Wt[c * OUTC + lane], w1 = Wt[c * OUTC + 64 + lane];
                a0 = fmaf(ca, w0, a0); a1 = fmaf(ca, w1, a1);
                b0 = fmaf(cb, w0, b0); b1 = fmaf(cb, w1, b1);
            }
            G[(size_t)pA * OUTC + lane]      = a0;
            G[(size_t)pA * OUTC + 64 + lane] = a1;
            G[(size_t)pB * OUTC + lane]      = b0;
            G[(size_t)pB * OUTC + 64 + lane] = b1;
        }
        return;
    }

    // ------- FPS path -------
    float4*             spt   = (float4*)sm;                        // [8192]
    unsigned short*     sorig = (unsigned short*)((char*)sm + 131072);
    unsigned long long* skey  = (unsigned long long*)((char*)sm + 147456); // [2][8]
    int*                s_misc = (int*)((char*)sm + 147584);

    const int b = blockIdx.x;

    if (w == 0) {
        // pass A: count masked points (wave 0 only)
        int nm_total = 0;
        for (int c = 0; c < 128; ++c) {
            int km = key_mask[b * NN + c * 64 + lane];
            nm_total += (int)__popcll(__ballot(km != 0));
        }
        const int NU0 = NN - nm_total;
        if (lane == 0) *s_misc = NU0;

        // pass B: stable partition (unmasked by idx, then masked by idx) + scale
        int nu_seen = 0, nm_seen = 0;
        for (int c = 0; c < 128; ++c) {
            int orig = c * 64 + lane;
            const float* p = xyz + ((size_t)b * NN + orig) * 3;
            float x = p[0], y = p[1], z = p[2];
            int km = key_mask[b * NN + orig];
            float off = km ? ((float)orig + 10.0f) * 10.0f : 0.0f;  // exact
            unsigned long long bm = __ballot(km != 0);
            int below = (int)__popcll(bm & ((1ull << lane) - 1ull));
            int pos = km ? (NU0 + nm_seen + below) : (nu_seen + (lane - below));
            spt[pos] = make_float4(x + off, y + off, z + off, 1e10f);
            sorig[pos] = (unsigned short)orig;
            int cm = (int)__popcll(bm);
            nm_seen += cm; nu_seen += 64 - cm;
        }
    }
    __syncthreads();
    const int NU = *s_misc;

    // pass C: own buckets' bbox + initial key -> REGISTERS
    // lane L holds bucket ((L&15)<<3)|w (replicated across the 4 lane rows)
    float rlox = 0.f, rloy = 0.f, rloz = 0.f, rhix = 0.f, rhiy = 0.f, rhiz = 0.f;
    unsigned long long rkey = 0;
    for (int i = 0; i < 16; ++i) {
        int j = (i << 3) | w;
        int p = (j << 6) + lane;
        float4 pt = spt[p];
        float lx = wred_minf(pt.x), hx = wred_maxf(pt.x);
        float ly = wred_minf(pt.y), hy = wred_maxf(pt.y);
        float lz = wred_minf(pt.z), hz = wred_maxf(pt.z);
        unsigned long long k = wbcast_maxu64(pack_key(1e10f, sorig[p], (unsigned)p));
        if ((lane & 15) == i) {
            rlox = lx; rhix = hx; rloy = ly; rhiy = hy; rloz = lz; rhiz = hz;
            rkey = k;
        }
    }
    unsigned long long wmax = row16_maxu64(rkey);   // lane15/31/47/63 valid

    // initial query = orig index 0
    int km0 = key_mask[b * NN];
    int pos0 = km0 ? NU : 0;
    float4 q0 = spt[pos0];
    float qx = q0.x, qy = q0.y, qz = q0.z;
    int s_last = 0;

    for (int it = 0; it < MM; ++it) {
        if (t == 0) fps_idx[b * MM + it] = s_last;

        // phase 1: skip tests, ALL-REGISTER (no LDS)
        float dmax = __uint_as_float((unsigned)(rkey >> 32));
        float dx = fmaxf(fmaxf(rlox - qx, qx - rhix), 0.f);
        float dy = fmaxf(fmaxf(rloy - qy, qy - rhiy), 0.f);
        float dz = fmaxf(fmaxf(rloz - qz, qz - rhiz), 0.f);
        float lb = distsq(dx, dy, dz);
        unsigned long long pend = __ballot(lb < dmax) & 0xFFFFull;

        // phase 2: update own pending buckets (cooperative 64-lane pass each)
        bool upd = (pend != 0);
        while (pend) {
            int i = __ffsll(pend) - 1; pend &= pend - 1;
            int jj = (i << 3) | w;
            int p = (jj << 6) + lane;
            float4 pt = spt[p];
            float d   = distsq(pt.x - qx, pt.y - qy, pt.z - qz);
            float dmn = fminf(pt.w, d);
            ((float*)(spt + p))[3] = dmn;        // write dmin (.w) only
            unsigned long long k = wbcast_maxu64(pack_key(dmn, sorig[p], (unsigned)p));
            if ((lane & 15) == i) rkey = k;
        }
        // per-wave pre-reduction (only when this wave updated something)
        if (upd) wmax = row16_maxu64(rkey);
        unsigned long long* kcur = skey + (it & 1) * 8;
        if (lane == 15) kcur[w] = wmax;
        __syncthreads();                         // the only barrier

        // phase 3: global argmax over 8 per-wave keys (uniform broadcast reads)
        ulonglong2 kA = *(const ulonglong2*)(kcur + 0);
        ulonglong2 kB = *(const ulonglong2*)(kcur + 2);
        ulonglong2 kC = *(const ulonglong2*)(kcur + 4);
        ulonglong2 kD = *(const ulonglong2*)(kcur + 6);
        unsigned long long m0 = kA.x > kA.y ? kA.x : kA.y;
        unsigned long long m1 = kB.x > kB.y ? kB.x : kB.y;
        unsigned long long m2 = kC.x > kC.y ? kC.x : kC.y;
        unsigned long long m3 = kD.x > kD.y ? kD.x : kD.y;
        m0 = m0 > m1 ? m0 : m1;
        m2 = m2 > m3 ? m2 : m3;
        unsigned long long kk = m0 > m2 ? m0 : m2;
        s_last = 8191 - (int)((kk >> 13) & 8191u);
        int pos = (int)(kk & 8191u);
        float4 qq = spt[pos];                    // uniform b128 (x,y,z used)
        qx = qq.x; qy = qq.y; qz = qq.z;
    }
}

// ---------------------------------------------------------------------------
// K3: fused ball query + gather + (G + gxyz*Wxyz + b) + LeakyReLU + pool.
// ---------------------------------------------------------------------------
__global__ __launch_bounds__(256) void group_kernel(
    const float* __restrict__ xyz, const int* __restrict__ mask,
    const int* __restrict__ key_mask, const float* __restrict__ W,
    const float* __restrict__ bias, const int* __restrict__ fps_idx,
    const float* __restrict__ G, float* __restrict__ out)
{
    __shared__ int s_idx[4][NS];
    const int t = threadIdx.x, lane = t & 63, w = t >> 6;
    const int q = blockIdx.x * 4 + w;         // 0..16383
    const int b = q >> 11;
    const int gi = fps_idx[q];

    const float* xb = xyz + (size_t)b * NN * 3;
    const float* qp = xb + (size_t)gi * 3;
    const float qx = qp[0], qy = qp[1], qz = qp[2];

    float* out0 = out;
    float* onx  = out  + (size_t)BB * MM * OUTC;
    float* onm  = onx  + (size_t)BB * MM * 3;
    float* onk  = onm  + (size_t)BB * MM;
    if (lane == 0) {
        onx[(size_t)q * 3 + 0] = qx;
        onx[(size_t)q * 3 + 1] = qy;
        onx[(size_t)q * 3 + 2] = qz;
        onm[q] = (float)mask[b * NN + gi];
        onk[q] = (float)key_mask[b * NN + gi];
    }

    const float q2 = qx * qx + qy * qy + qz * qz;
    int have = 0, idx0 = -1;
    for (int base = 0; base < NN; base += 64) {
        int n = base + lane;
        const float* p = xb + n * 3;
        float x = p[0], y = p[1], z = p[2];
        float p2 = x * x + y * y + z * z;
        float dt = qx * x + qy * y + qz * z;
        float d2 = (q2 + p2) - 2.0f * dt;
        bool within = d2 < 0.25f;
        unsigned long long bm = __ballot(within);
        if (bm) {
            if (idx0 < 0) idx0 = base + (__ffsll(bm) - 1);
            if (within) {
                int pos = have + __popcll(bm & ((1ull << lane) - 1ull));
                if (pos < NS) s_idx[w][pos] = n;
            }
            have += (int)__popcll(bm);
            if (have >= NS) break;
        }
    }
    if (have > NS) have = NS;
    if (lane >= have && lane < NS) s_idx[w][lane] = idx0;   // pad with first valid
    __asm__ volatile("s_waitcnt lgkmcnt(0)" ::: "memory");  // LDS writes visible

    const float w0x = W[lane * 67 + 64], w0y = W[lane * 67 + 65], w0z = W[lane * 67 + 66];
    const float w1x = W[(lane + 64) * 67 + 64], w1y = W[(lane + 64) * 67 + 65], w1z = W[(lane + 64) * 67 + 66];
    const float b0 = bias[lane], b1 = bias[lane + 64];
    const float* Gb = G + (size_t)b * NN * OUTC;

    float acc = 0.f, mx = -3.4e38f;
    #pragma unroll 4
    for (int s = 0; s < NS; ++s) {
        int id = s_idx[w][s];
        const float* pr = xb + (size_t)id * 3;
        float dx = pr[0] - qx, dy = pr[1] - qy, dz = pr[2] - qz;
        const float* g = Gb + (size_t)id * OUTC;
        float y0 = g[lane]      + dx * w0x + dy * w0y + dz * w0z + b0;
        float y1 = g[lane + 64] + dx * w1x + dy * w1y + dz * w1z + b1;
        y0 = y0 > 0.f ? y0 : 0.01f * y0;
        y1 = y1 > 0.f ? y1 : 0.01f * y1;
        acc += y0;
        mx = fmaxf(mx, y1);
    }
    out0[(size_t)q * OUTC + lane]      = acc * (1.0f / 32.0f);
    out0[(size_t)q * OUTC + 64 + lane] = mx;
}

// ---------------------------------------------------------------------------
extern "C" void kernel_launch(void* const* d_in, const int* in_sizes, int n_in,
                              void* d_out, int out_size, void* d_ws, size_t ws_size,
                              hipStream_t stream)
{
    const float* feat  = (const float*)d_in[0];
    const float* xyz   = (const float*)d_in[1];
    const int*   mask  = (const int*)d_in[2];
    const int*   kmask = (const int*)d_in[3];
    const float* W     = (const float*)d_in[4];
    const float* bias  = (const float*)d_in[5];
    float* out = (float*)d_out;

    int*   fps_idx = (int*)d_ws;                          // 64 KB
    float* G       = (float*)((char*)d_ws + 65536);       // 32 MB

    // opt-in to >64KB dynamic LDS (host-side setting; graph-capture safe)
    hipFuncSetAttribute((const void*)fps_featw_kernel,
                        hipFuncAttributeMaxDynamicSharedMemorySize, FPS_LDS_BYTES);

    hipLaunchKernelGGL(fps_featw_kernel, dim3(BB + 32), dim3(FPS_T), FPS_LDS_BYTES, stream,
                       xyz, kmask, feat, W, fps_idx, G);
    hipLaunchKernelGGL(group_kernel, dim3(4096), dim3(256), 0, stream,
                       xyz, mask, kmask, W, bias, fps_idx, G, out);
}

// Round 10
// 1254.564 us; speedup vs baseline: 1.2388x; 1.2388x over previous
//
#include <hip/hip_runtime.h>

// Problem constants (fixed by the reference)
#define BB    8
#define NN    8192
#define MM    2048
#define CFEAT 64
#define OUTC  128
#define NS    32
#define NBUCK 128     // buckets per batch; bucket j owned by wave (j & 7)
#define FPS_T 512     // 8 waves

// ---------------------------------------------------------------------------
// DPP wave64 reductions. Chain: row_shr 1/2/4/8 + bcast15 + bcast31; lane63
// holds the full reduction. bound_ctrl=false + old=self => identity fill.
// ---------------------------------------------------------------------------
template<int C, int R>
__device__ __forceinline__ float dpp_maxf(float v) {
    int t = __builtin_amdgcn_update_dpp(__float_as_int(v), __float_as_int(v), C, R, 0xf, false);
    return fmaxf(v, __int_as_float(t));
}
template<int C, int R>
__device__ __forceinline__ float dpp_minf(float v) {
    int t = __builtin_amdgcn_update_dpp(__float_as_int(v), __float_as_int(v), C, R, 0xf, false);
    return fminf(v, __int_as_float(t));
}
template<int C, int R>
__device__ __forceinline__ unsigned dpp_maxu(unsigned v) {
    unsigned t = (unsigned)__builtin_amdgcn_update_dpp((int)v, (int)v, C, R, 0xf, false);
    return v > t ? v : t;
}
template<int C, int R>
__device__ __forceinline__ unsigned dpp_minu(unsigned v) {
    unsigned t = (unsigned)__builtin_amdgcn_update_dpp((int)v, (int)v, C, R, 0xf, false);
    return v < t ? v : t;
}
template<int C, int R>
__device__ __forceinline__ unsigned long long dpp_maxu64(unsigned long long v) {
    unsigned lo = (unsigned)v, hi = (unsigned)(v >> 32);
    unsigned tlo = (unsigned)__builtin_amdgcn_update_dpp((int)lo, (int)lo, C, R, 0xf, false);
    unsigned thi = (unsigned)__builtin_amdgcn_update_dpp((int)hi, (int)hi, C, R, 0xf, false);
    unsigned long long t = ((unsigned long long)thi << 32) | tlo;
    return t > v ? t : v;
}
__device__ __forceinline__ float wred_maxf(float v) {
    v = dpp_maxf<0x111,0xf>(v); v = dpp_maxf<0x112,0xf>(v);
    v = dpp_maxf<0x114,0xf>(v); v = dpp_maxf<0x118,0xf>(v);
    v = dpp_maxf<0x142,0xa>(v); v = dpp_maxf<0x143,0xc>(v);
    return __int_as_float(__builtin_amdgcn_readlane(__float_as_int(v), 63));
}
__device__ __forceinline__ float wred_minf(float v) {
    v = dpp_minf<0x111,0xf>(v); v = dpp_minf<0x112,0xf>(v);
    v = dpp_minf<0x114,0xf>(v); v = dpp_minf<0x118,0xf>(v);
    v = dpp_minf<0x142,0xa>(v); v = dpp_minf<0x143,0xc>(v);
    return __int_as_float(__builtin_amdgcn_readlane(__float_as_int(v), 63));
}
// u32 chains + broadcast (single-instruction DPP steps — the fast primitive)
__device__ __forceinline__ unsigned wred_maxu32(unsigned v) {
    v = dpp_maxu<0x111,0xf>(v); v = dpp_maxu<0x112,0xf>(v);
    v = dpp_maxu<0x114,0xf>(v); v = dpp_maxu<0x118,0xf>(v);
    v = dpp_maxu<0x142,0xa>(v); v = dpp_maxu<0x143,0xc>(v);
    return (unsigned)__builtin_amdgcn_readlane((int)v, 63);
}
__device__ __forceinline__ unsigned wred_minu32(unsigned v) {
    v = dpp_minu<0x111,0xf>(v); v = dpp_minu<0x112,0xf>(v);
    v = dpp_minu<0x114,0xf>(v); v = dpp_minu<0x118,0xf>(v);
    v = dpp_minu<0x142,0xa>(v); v = dpp_minu<0x143,0xc>(v);
    return (unsigned)__builtin_amdgcn_readlane((int)v, 63);
}
// full 64-lane u64 chain + broadcast (setup only)
__device__ __forceinline__ unsigned long long wbcast_maxu64(unsigned long long v) {
    v = dpp_maxu64<0x111,0xf>(v); v = dpp_maxu64<0x112,0xf>(v);
    v = dpp_maxu64<0x114,0xf>(v); v = dpp_maxu64<0x118,0xf>(v);
    v = dpp_maxu64<0x142,0xa>(v); v = dpp_maxu64<0x143,0xc>(v);
    unsigned lo = (unsigned)__builtin_amdgcn_readlane((int)(unsigned)v, 63);
    unsigned hi = (unsigned)__builtin_amdgcn_readlane((int)(unsigned)(v >> 32), 63);
    return ((unsigned long long)hi << 32) | lo;
}

// identical fma shape for point distance and bbox lower bound => lb2 <= d2
// holds in f32 by per-op monotonicity (safe exact skipping).
__device__ __forceinline__ float distsq(float dx, float dy, float dz) {
    return fmaf(dz, dz, fmaf(dy, dy, dx * dx));
}

// key layout: (dmin_bits << 32) | ((8191-orig) << 13) | pos
// u64 max  =>  max dmin, ties -> min orig (orig unique => total order).
__device__ __forceinline__ unsigned long long pack_key(float dmn, unsigned orig, unsigned pos) {
    return ((unsigned long long)__float_as_uint(dmn) << 32)
         | ((unsigned long long)(8191u - orig) << 13) | pos;
}

// ---------------------------------------------------------------------------
// LDS layout (byte offsets), FPS path (identical to R8):
//   spt    [8192] float4 (x,y,z,dmin)       0   131072 B
//   sorig  [8192] u16               131072    16384 B
//   skey   [2][128] u64 (parity)    147456     2048 B
//   s_misc [4] i32                  149504       16 B
// ---------------------------------------------------------------------------
#define FPS_LDS_BYTES 149760

__global__ __launch_bounds__(FPS_T) void fps_featw_kernel(
    const float* __restrict__ xyz, const int* __restrict__ key_mask,
    const float* __restrict__ feat, const float* __restrict__ W,
    int* __restrict__ fps_idx, float* __restrict__ G)
{
    extern __shared__ float sm[];
    const int t    = threadIdx.x;
    const int lane = t & 63;
    const int w    = t >> 6;

    if (blockIdx.x >= BB) {
        // ------- featW path: 32 blocks x 8 waves x 256 pts -------
        float* Wt = sm;   // [c][o], 32 KB
        for (int i = t; i < CFEAT * OUTC; i += FPS_T) {
            int c = i >> 7, o = i & 127;
            Wt[i] = W[o * 67 + c];
        }
        __syncthreads();
        const int p0 = (blockIdx.x - BB) * 2048 + w * 256;
        for (int k = 0; k < 256; k += 2) {
            int pA = p0 + k, pB = pA + 1;
            float fa = feat[(size_t)pA * CFEAT + lane];
            float fb = feat[(size_t)pB * CFEAT + lane];
            float a0 = 0.f, a1 = 0.f, b0 = 0.f, b1 = 0.f;
            #pragma unroll 8
            for (int c = 0; c < CFEAT; ++c) {
                float ca = __shfl(fa, c), cb = __shfl(fb, c);
                float w0 = Wt[c * OUTC + lane], w1 = Wt[c * OUTC + 64 + lane];
                a0 = fmaf(ca, w0, a0); a1 = fmaf(ca, w1, a1);
                b0 = fmaf(cb, w0, b0); b1 = fmaf(cb, w1, b1);
            }
            G[(size_t)pA * OUTC + lane]      = a0;
            G[(size_t)pA * OUTC + 64 + lane] = a1;
            G[(size_t)pB * OUTC + lane]      = b0;
            G[(size_t)pB * OUTC + 64 + lane] = b1;
        }
        return;
    }

    // ------- FPS path -------
    float4*             spt   = (float4*)sm;                        // [8192]
    unsigned short*     sorig = (unsigned short*)((char*)sm + 131072);
    unsigned long long* skey  = (unsigned long long*)((char*)sm + 147456); // [2][128]
    int*                s_misc = (int*)((char*)sm + 149504);

    const int b = blockIdx.x;

    if (w == 0) {
        // pass A: count masked points (wave 0 only)
        int nm_total = 0;
        for (int c = 0; c < 128; ++c) {
            int km = key_mask[b * NN + c * 64 + lane];
            nm_total += (int)__popcll(__ballot(km != 0));
        }
        const int NU0 = NN - nm_total;
        if (lane == 0) *s_misc = NU0;

        // pass B: stable partition (unmasked by idx, then masked by idx) + scale
        int nu_seen = 0, nm_seen = 0;
        for (int c = 0; c < 128; ++c) {
            int orig = c * 64 + lane;
            const float* p = xyz + ((size_t)b * NN + orig) * 3;
            float x = p[0], y = p[1], z = p[2];
            int km = key_mask[b * NN + orig];
            float off = km ? ((float)orig + 10.0f) * 10.0f : 0.0f;  // exact
            unsigned long long bm = __ballot(km != 0);
            int below = (int)__popcll(bm & ((1ull << lane) - 1ull));
            int pos = km ? (NU0 + nm_seen + below) : (nu_seen + (lane - below));
            spt[pos] = make_float4(x + off, y + off, z + off, 1e10f);
            sorig[pos] = (unsigned short)orig;
            int cm = (int)__popcll(bm);
            nm_seen += cm; nu_seen += 64 - cm;
        }
    }
    __syncthreads();
    const int NU = *s_misc;

    // pass C: own buckets' bbox + initial key -> REGISTERS
    // lane L holds bucket ((L&15)<<3)|w (replicated across the 4 lane rows)
    float rlox = 0.f, rloy = 0.f, rloz = 0.f, rhix = 0.f, rhiy = 0.f, rhiz = 0.f;
    unsigned long long rkey = 0;
    for (int i = 0; i < 16; ++i) {
        int j = (i << 3) | w;
        int p = (j << 6) + lane;
        float4 pt = spt[p];
        float lx = wred_minf(pt.x), hx = wred_maxf(pt.x);
        float ly = wred_minf(pt.y), hy = wred_maxf(pt.y);
        float lz = wred_minf(pt.z), hz = wred_maxf(pt.z);
        unsigned long long k = wbcast_maxu64(pack_key(1e10f, sorig[p], (unsigned)p));
        if ((lane & 15) == i) {
            rlox = lx; rhix = hx; rloy = ly; rhiy = hy; rloz = lz; rhiz = hz;
            rkey = k;
        }
    }

    // initial query = orig index 0
    int km0 = key_mask[b * NN];
    int pos0 = km0 ? NU : 0;
    float4 q0 = spt[pos0];
    float qx = q0.x, qy = q0.y, qz = q0.z;
    int s_last = 0;

    for (int it = 0; it < MM; ++it) {
        if (t == 0) fps_idx[b * MM + it] = s_last;

        // phase 1: skip tests, ALL-REGISTER (no LDS)
        float dmax = __uint_as_float((unsigned)(rkey >> 32));
        float dx = fmaxf(fmaxf(rlox - qx, qx - rhix), 0.f);
        float dy = fmaxf(fmaxf(rloy - qy, qy - rhiy), 0.f);
        float dz = fmaxf(fmaxf(rloz - qz, qz - rhiz), 0.f);
        float lb = distsq(dx, dy, dz);
        unsigned long long pend = __ballot(lb < dmax) & 0xFFFFull;

        // phase 2: update own pending buckets. Fast path: u32 DPP max over
        // dmin bits (single-instr steps), winner index via ballot+readlane.
        // Slow path (exact ties, e.g. 1e10 epoch): u32 min chain over packed
        // (orig<<6|lane). Semantics identical to the u64-key max of R5-R8.
        while (pend) {
            int i = __ffsll(pend) - 1; pend &= pend - 1;
            int jj = (i << 3) | w;
            int p = (jj << 6) + lane;
            float4 pt = spt[p];
            unsigned og = sorig[p];              // co-issued with spt load
            float d   = distsq(pt.x - qx, pt.y - qy, pt.z - qz);
            float dmn = fminf(pt.w, d);
            ((float*)(spt + p))[3] = dmn;        // write dmin (.w) only
            unsigned A  = __float_as_uint(dmn);  // dmn >= 0 => u32 cmp == f32 cmp
            unsigned Am = wred_maxu32(A);
            unsigned long long mk = __ballot(A == Am);
            unsigned lo;
            if (__popcll(mk) == 1) {             // wave-uniform branch
                int wl = __ffsll(mk) - 1;
                unsigned ogw = (unsigned)__builtin_amdgcn_readlane((int)og, wl);
                lo = ((8191u - ogw) << 13) | (unsigned)((jj << 6) + wl);
            } else {
                unsigned Cv = (A == Am) ? ((og << 6) | (unsigned)lane) : 0xffffffffu;
                unsigned Cm = wred_minu32(Cv);   // min orig (unique) among achievers
                lo = ((8191u - (Cm >> 6)) << 13) | (unsigned)((jj << 6) + (Cm & 63u));
            }
            unsigned long long k = ((unsigned long long)Am << 32) | lo;
            if ((lane & 15) == i) rkey = k;
        }
        // dump own 16 keys (registers -> parity buffer; contiguous, no conflict)
        unsigned long long* kcur = skey + (it & 1) * NBUCK;
        if (lane < 16) kcur[w * 16 + lane] = rkey;
        __syncthreads();                         // the only barrier

        // phase 3: global argmax over 128 keys — same u32-chain trick
        unsigned long long k0 = kcur[lane];
        unsigned long long k1 = kcur[lane + 64];
        unsigned long long km = k0 > k1 ? k0 : k1;
        unsigned A  = (unsigned)(km >> 32);
        unsigned Am = wred_maxu32(A);
        unsigned long long mk = __ballot(A == Am);
        unsigned lo;
        if (__popcll(mk) == 1) {
            int wl = __ffsll(mk) - 1;
            lo = (unsigned)__builtin_amdgcn_readlane((int)(unsigned)km, wl);
        } else {
            unsigned Lv = (A == Am) ? (unsigned)km : 0u;
            unsigned Lm = dpp_maxu<0x111,0xf>(Lv);
            Lm = dpp_maxu<0x112,0xf>(Lm); Lm = dpp_maxu<0x114,0xf>(Lm);
            Lm = dpp_maxu<0x118,0xf>(Lm); Lm = dpp_maxu<0x142,0xa>(Lm);
            Lm = dpp_maxu<0x143,0xc>(Lm);
            lo = (unsigned)__builtin_amdgcn_readlane((int)Lm, 63);
        }
        s_last = 8191 - (int)((lo >> 13) & 8191u);
        int pos = (int)(lo & 8191u);
        float4 qq = spt[pos];                    // uniform b128 (x,y,z used)
        qx = qq.x; qy = qq.y; qz = qq.z;
    }
}

// ---------------------------------------------------------------------------
// K3: fused ball query + gather + (G + gxyz*Wxyz + b) + LeakyReLU + pool.
// ---------------------------------------------------------------------------
__global__ __launch_bounds__(256) void group_kernel(
    const float* __restrict__ xyz, const int* __restrict__ mask,
    const int* __restrict__ key_mask, const float* __restrict__ W,
    const float* __restrict__ bias, const int* __restrict__ fps_idx,
    const float* __restrict__ G, float* __restrict__ out)
{
    __shared__ int s_idx[4][NS];
    const int t = threadIdx.x, lane = t & 63, w = t >> 6;
    const int q = blockIdx.x * 4 + w;         // 0..16383
    const int b = q >> 11;
    const int gi = fps_idx[q];

    const float* xb = xyz + (size_t)b * NN * 3;
    const float* qp = xb + (size_t)gi * 3;
    const float qx = qp[0], qy = qp[1], qz = qp[2];

    float* out0 = out;
    float* onx  = out  + (size_t)BB * MM * OUTC;
    float* onm  = onx  + (size_t)BB * MM * 3;
    float* onk  = onm  + (size_t)BB * MM;
    if (lane == 0) {
        onx[(size_t)q * 3 + 0] = qx;
        onx[(size_t)q * 3 + 1] = qy;
        onx[(size_t)q * 3 + 2] = qz;
        onm[q] = (float)mask[b * NN + gi];
        onk[q] = (float)key_mask[b * NN + gi];
    }

    const float q2 = qx * qx + qy * qy + qz * qz;
    int have = 0, idx0 = -1;
    for (int base = 0; base < NN; base += 64) {
        int n = base + lane;
        const float* p = xb + n * 3;
        float x = p[0], y = p[1], z = p[2];
        float p2 = x * x + y * y + z * z;
        float dt = qx * x + qy * y + qz * z;
        float d2 = (q2 + p2) - 2.0f * dt;
        bool within = d2 < 0.25f;
        unsigned long long bm = __ballot(within);
        if (bm) {
            if (idx0 < 0) idx0 = base + (__ffsll(bm) - 1);
            if (within) {
                int pos = have + __popcll(bm & ((1ull << lane) - 1ull));
                if (pos < NS) s_idx[w][pos] = n;
            }
            have += (int)__popcll(bm);
            if (have >= NS) break;
        }
    }
    if (have > NS) have = NS;
    if (lane >= have && lane < NS) s_idx[w][lane] = idx0;   // pad with first valid
    __asm__ volatile("s_waitcnt lgkmcnt(0)" ::: "memory");  // LDS writes visible

    const float w0x = W[lane * 67 + 64], w0y = W[lane * 67 + 65], w0z = W[lane * 67 + 66];
    const float w1x = W[(lane + 64) * 67 + 64], w1y = W[(lane + 64) * 67 + 65], w1z = W[(lane + 64) * 67 + 66];
    const float b0 = bias[lane], b1 = bias[lane + 64];
    const float* Gb = G + (size_t)b * NN * OUTC;

    float acc = 0.f, mx = -3.4e38f;
    #pragma unroll 4
    for (int s = 0; s < NS; ++s) {
        int id = s_idx[w][s];
        const float* pr = xb + (size_t)id * 3;
        float dx = pr[0] - qx, dy = pr[1] - qy, dz = pr[2] - qz;
        const float* g = Gb + (size_t)id * OUTC;
        float y0 = g[lane]      + dx * w0x + dy * w0y + dz * w0z + b0;
        float y1 = g[lane + 64] + dx * w1x + dy * w1y + dz * w1z + b1;
        y0 = y0 > 0.f ? y0 : 0.01f * y0;
        y1 = y1 > 0.f ? y1 : 0.01f * y1;
        acc += y0;
        mx = fmaxf(mx, y1);
    }
    out0[(size_t)q * OUTC + lane]      = acc * (1.0f / 32.0f);
    out0[(size_t)q * OUTC + 64 + lane] = mx;
}

// ---------------------------------------------------------------------------
extern "C" void kernel_launch(void* const* d_in, const int* in_sizes, int n_in,
                              void* d_out, int out_size, void* d_ws, size_t ws_size,
                              hipStream_t stream)
{
    const float* feat  = (const float*)d_in[0];
    const float* xyz   = (const float*)d_in[1];
    const int*   mask  = (const int*)d_in[2];
    const int*   kmask = (const int*)d_in[3];
    const float* W     = (const float*)d_in[4];
    const float* bias  = (const float*)d_in[5];
    float* out = (float*)d_out;

    int*   fps_idx = (int*)d_ws;                          // 64 KB
    float* G       = (float*)((char*)d_ws + 65536);       // 32 MB

    // opt-in to >64KB dynamic LDS (host-side setting; graph-capture safe)
    hipFuncSetAttribute((const void*)fps_featw_kernel,
                        hipFuncAttributeMaxDynamicSharedMemorySize, FPS_LDS_BYTES);

    hipLaunchKernelGGL(fps_featw_kernel, dim3(BB + 32), dim3(FPS_T), FPS_LDS_BYTES, stream,
                       xyz, kmask, feat, W, fps_idx, G);
    hipLaunchKernelGGL(group_kernel, dim3(4096), dim3(256), 0, stream,
                       xyz, mask, kmask, W, bias, fps_idx, G, out);
}